// Round 7
// baseline (287.067 us; speedup 1.0000x reference)
//
#include <hip/hip_runtime.h>
#include <hip/hip_bf16.h>
#include <stdint.h>

#define B_SZ   2
#define S_LEN  2048
#define DMODEL 2048
#define NH     16
#define DHD    128

typedef __attribute__((ext_vector_type(8))) __bf16 bf16x8;
typedef __attribute__((ext_vector_type(4))) float  f32x4;
typedef __attribute__((ext_vector_type(4))) float  float4v;
typedef __attribute__((ext_vector_type(8))) unsigned short ushort8;
typedef __attribute__((ext_vector_type(4))) unsigned short ushort4v;

__device__ __forceinline__ unsigned short f2bf(float f) {
  unsigned int u = __float_as_uint(f);
  unsigned int r = (u + 0x7fffu + ((u >> 16) & 1u)) >> 16;
  return (unsigned short)r;
}

__device__ __forceinline__ unsigned int cvt_pk_bf16(float lo, float hi) {
  unsigned int r;
  asm("v_cvt_pk_bf16_f32 %0, %1, %2" : "=v"(r) : "v"(lo), "v"(hi));
  return r;
}

__device__ __forceinline__ void async_cp16(void* lds, const void* g) {
  __builtin_amdgcn_global_load_lds(
      (const __attribute__((address_space(1))) void*)g,
      (__attribute__((address_space(3))) void*)lds, 16, 0, 0);
}

// ---------------- elementwise cast x -> bf16 ----------------
__global__ __launch_bounds__(256) void k_cast_bf16(const float* __restrict__ in,
                                                   unsigned short* __restrict__ out,
                                                   int n4) {
  int i = blockIdx.x * 256 + threadIdx.x;
  if (i >= n4) return;
  float4v v = ((const float4v*)in)[i];
  ushort4v o;
  o[0] = f2bf(v[0]); o[1] = f2bf(v[1]); o[2] = f2bf(v[2]); o[3] = f2bf(v[3]);
  ((ushort4v*)out)[i] = o;
}

// ---- transpose + cast all four weights: W[K][N] -> WT[N][K] bf16 (z-batched) ----
__global__ __launch_bounds__(256) void k_transpose_all(const float* __restrict__ w0,
                                                       const float* __restrict__ w1,
                                                       const float* __restrict__ w2,
                                                       const float* __restrict__ w3,
                                                       unsigned short* __restrict__ WTbase) {
  __shared__ unsigned short tile[64 * 72];
  const int z = blockIdx.z;
  const float* W = (z == 0) ? w0 : (z == 1) ? w1 : (z == 2) ? w2 : w3;
  unsigned short* WT = WTbase + (size_t)z * 4194304;
  const int n0 = blockIdx.x * 64;
  const int k0 = blockIdx.y * 64;
  const int t = threadIdx.x;
#pragma unroll
  for (int i = 0; i < 4; ++i) {
    int c = t + 256 * i;
    int r = c >> 4, c4 = c & 15;
    float4v v = *(const float4v*)(W + (size_t)(k0 + r) * DMODEL + n0 + c4 * 4);
    ushort4v o;
    o[0] = f2bf(v[0]); o[1] = f2bf(v[1]); o[2] = f2bf(v[2]); o[3] = f2bf(v[3]);
    *(ushort4v*)(&tile[r * 72 + c4 * 4]) = o;
  }
  __syncthreads();
#pragma unroll
  for (int i = 0; i < 2; ++i) {
    int c = t + 256 * i;
    int n = c >> 3, k8 = c & 7;
    ushort8 o;
#pragma unroll
    for (int j = 0; j < 8; ++j) o[j] = tile[(k8 * 8 + j) * 72 + n];
    *(ushort8*)(WT + (size_t)(n0 + n) * DMODEL + k0 + k8 * 8) = o;
  }
}

// ---------------- rope cos/sin table [S][64] ----------------
__global__ __launch_bounds__(256) void k_rope_table(float* __restrict__ cosT,
                                                    float* __restrict__ sinT) {
  int i = blockIdx.x * 256 + threadIdx.x;  // < S_LEN*64
  int s = i >> 6, dj = i & 63;
  float e = __expf(-9.210340371976184f * (float)dj * (1.0f / 64.0f)); // 10000^{-dj/64}
  float f = (float)s * e;
  cosT[i] = cosf(f);
  sinT[i] = sinf(f);
}

// ---------------- 256x256x64 2-barrier look-ahead GEMM (qkv) ----------------
// C[4096][6144] = A * [wqT;wkT;wvT]^T. 512 thr, 8 waves (2M x 4N),
// per-wave 128x64, acc[8][4]=128 VGPR. LDS 128 KiB dbuf {A 32K, B 32K}.
// Per tile: p0 reads b0,a0,b1 + STG_A(t+1->other) + lgkm(4) + 32 MFMA;
// barrier; p1 lgkm(0) + STG_B(t+2->cur) + read a1 + lgkm(0) + 32 MFMA + vmcnt(4).
__global__ __launch_bounds__(512, 2) void k_gemm256(
    const unsigned short* __restrict__ A,
    const unsigned short* __restrict__ BT,
    unsigned short* __restrict__ Cq,
    unsigned short* __restrict__ Ck,
    unsigned short* __restrict__ Cv,
    const float* __restrict__ cosT,
    const float* __restrict__ sinT) {
  __shared__ char smem[131072];
  const int tid = threadIdx.x;

  // XCD chunk: 8 XCDs as 4(bm-groups of 4) x 2(bn-halves of 12)
  const int xcd = blockIdx.x & 7;
  const int idx = blockIdx.x >> 3;           // [0, 48)
  const int bm = (xcd >> 1) * 4 + (idx & 3);
  const int bn = (xcd & 1) * 12 + (idx >> 2);

  // ---- staging addressing ----
  const int gs = (tid & 7) ^ ((tid >> 3) & 7);
  const unsigned short* Abase = A + (size_t)(bm * 256 + (tid >> 3)) * 2048 + gs * 8;
  const unsigned short* Bbase = BT + (size_t)(bn * 256 + (tid >> 3)) * 2048 + gs * 8;
  const int dstA = tid * 16;
  const int dstB = 32768 + tid * 16;

  // ---- fragment addressing (base + m*2048 imm; swizzle m-independent) ----
  const int lane = tid & 63, wid = tid >> 6;
  const int wr = wid >> 2, wcn = wid & 3;
  const int lr = lane & 15, hi = lane >> 4;
  const int sw0 = ((hi) ^ (lr & 7)) << 4;
  const int sw1 = ((4 + hi) ^ (lr & 7)) << 4;
  const int aB0 = (wr * 128 + lr) * 128 + sw0;
  const int aB1 = (wr * 128 + lr) * 128 + sw1;
  const int bB0 = 32768 + (wcn * 64 + lr) * 128 + sw0;
  const int bB1 = 32768 + (wcn * 64 + lr) * 128 + sw1;

  f32x4 acc[8][4];
#pragma unroll
  for (int m = 0; m < 8; ++m)
#pragma unroll
    for (int n = 0; n < 4; ++n) {
      f32x4 z = {0.f, 0.f, 0.f, 0.f};
      acc[m][n] = z;
    }

#define STG_A6(c, t_) do {                                                  \
    const unsigned short* _s = Abase + (t_) * 64;                           \
    async_cp16(smem + (c) * 65536 + dstA, _s);                              \
    async_cp16(smem + (c) * 65536 + dstA + 8192, _s + (size_t)64 * 2048);   \
    async_cp16(smem + (c) * 65536 + dstA + 16384, _s + (size_t)128 * 2048); \
    async_cp16(smem + (c) * 65536 + dstA + 24576, _s + (size_t)192 * 2048); \
  } while (0)
#define STG_B6(c, t_) do {                                                  \
    const unsigned short* _s = Bbase + (t_) * 64;                           \
    async_cp16(smem + (c) * 65536 + dstB, _s);                              \
    async_cp16(smem + (c) * 65536 + dstB + 8192, _s + (size_t)64 * 2048);   \
    async_cp16(smem + (c) * 65536 + dstB + 16384, _s + (size_t)128 * 2048); \
    async_cp16(smem + (c) * 65536 + dstB + 24576, _s + (size_t)192 * 2048); \
  } while (0)

  auto tile = [&](int T, int CC, bool DO_A, bool DO_B, int VM) __attribute__((always_inline)) {
    const char* Sb = smem + CC * 65536;
    bf16x8 a0[8], b0[4], b1[4];
    // p0: b0, a0, b1 reads (b1 early so STG_B after barrier is safe)
#pragma unroll
    for (int n = 0; n < 4; ++n) b0[n] = *(const bf16x8*)(Sb + bB0 + n * 2048);
#pragma unroll
    for (int m = 0; m < 8; ++m) a0[m] = *(const bf16x8*)(Sb + aB0 + m * 2048);
#pragma unroll
    for (int n = 0; n < 4; ++n) b1[n] = *(const bf16x8*)(Sb + bB1 + n * 2048);
    if (DO_A) STG_A6(CC ^ 1, T + 1);
    asm volatile("s_waitcnt lgkmcnt(4)" ::: "memory");
    __builtin_amdgcn_sched_barrier(0);
    __builtin_amdgcn_s_setprio(1);
#pragma unroll
    for (int m = 0; m < 8; ++m)
#pragma unroll
      for (int n = 0; n < 4; ++n)
        acc[m][n] = __builtin_amdgcn_mfma_f32_16x16x32_bf16(a0[m], b0[n], acc[m][n], 0, 0, 0);
    __builtin_amdgcn_s_setprio(0);
    __builtin_amdgcn_s_barrier();
    __builtin_amdgcn_sched_barrier(0);
    // p1: all waves' B reads done -> safe to overwrite B region of this buf
    asm volatile("s_waitcnt lgkmcnt(0)" ::: "memory");
    __builtin_amdgcn_sched_barrier(0);
    if (DO_B) STG_B6(CC, T + 2);
    bf16x8 a1[8];
#pragma unroll
    for (int m = 0; m < 8; ++m) a1[m] = *(const bf16x8*)(Sb + aB1 + m * 2048);
    asm volatile("s_waitcnt lgkmcnt(0)" ::: "memory");
    __builtin_amdgcn_sched_barrier(0);
    __builtin_amdgcn_s_setprio(1);
#pragma unroll
    for (int m = 0; m < 8; ++m)
#pragma unroll
      for (int n = 0; n < 4; ++n)
        acc[m][n] = __builtin_amdgcn_mfma_f32_16x16x32_bf16(a1[m], b1[n], acc[m][n], 0, 0, 0);
    __builtin_amdgcn_s_setprio(0);
    if (VM == 0) asm volatile("s_waitcnt vmcnt(4)" ::: "memory");
    else if (VM == 1) asm volatile("s_waitcnt vmcnt(0)" ::: "memory");
    if (VM != 2) {
      __builtin_amdgcn_s_barrier();
      __builtin_amdgcn_sched_barrier(0);
    }
  };

  // prologue: B(0),A(0) -> buf0; B(1) -> buf1
  STG_B6(0, 0);
  STG_A6(0, 0);
  STG_B6(1, 1);
  asm volatile("s_waitcnt vmcnt(4)" ::: "memory");
  __builtin_amdgcn_s_barrier();
  __builtin_amdgcn_sched_barrier(0);

  for (int it = 0; it < 15; ++it) {
    tile(2 * it, 0, true, true, 0);
    tile(2 * it + 1, 1, true, true, 0);
  }
  tile(30, 0, true, false, 1);
  tile(31, 1, false, false, 2);

  // ---- fused QKV epilogue ----
  const int row_b = bm * 256 + wr * 128 + hi * 4;
  const int col_b = bn * 256 + wcn * 64 + lr;
  const int sel = bn >> 3;  // 0:q 1:k 2:v
#pragma unroll
  for (int m = 0; m < 8; ++m) {
#pragma unroll
    for (int n = 0; n < 4; ++n) {
      int col = col_b + n * 16;
      int hh = (col >> 7) & 15, d = col & 127;
      if (sel == 2) {
#pragma unroll
        for (int j = 0; j < 4; ++j) {
          int row = row_b + m * 16 + j;
          int b = row >> 11, s = row & 2047;
          Cv[((size_t)(b * NH + hh) * S_LEN + s) * DHD + d] = f2bf(acc[m][n][j]);
        }
      } else {
        unsigned short* dst = sel ? Ck : Cq;
        int dj = d >> 1;
        float sgn = (d & 1) ? 1.f : -1.f;
#pragma unroll
        for (int j = 0; j < 4; ++j) {
          int row = row_b + m * 16 + j;
          int b = row >> 11, s = row & 2047;
          float v = acc[m][n][j];
          float pp = __shfl_xor(v, 1);
          float cc = cosT[(s << 6) + dj];
          float sn = sinT[(s << 6) + dj];
          dst[((size_t)(b * NH + hh) * S_LEN + s) * DHD + d] = f2bf(v * cc + sgn * pp * sn);
        }
      }
    }
  }
#undef STG_A6
#undef STG_B6
}

// ---------------- 128x256x64 2-phase look-ahead GEMM (wo, fp32 out) --------
__global__ __launch_bounds__(512, 2) void k_gemm128(
    const unsigned short* __restrict__ A,
    const unsigned short* __restrict__ BT,
    float* __restrict__ C0,
    int chn) {
  __shared__ char smem[98304];
  const int tid = threadIdx.x;

  const int xcd = blockIdx.x & 7;
  const int idx = blockIdx.x >> 3;
  const int bm = (xcd >> 2) * 16 + (idx & 15);
  const int bn = (xcd & 3) * chn + (idx >> 4);

  const int gs = (tid & 7) ^ ((tid >> 3) & 7);
  const unsigned short* Abase = A + (size_t)(bm * 128 + (tid >> 3)) * 2048 + gs * 8;
  const unsigned short* Bbase = BT + (size_t)(bn * 256 + (tid >> 3)) * 2048 + gs * 8;
  const int dstA = tid * 16;
  const int dstB = 16384 + tid * 16;

  const int lane = tid & 63, wid = tid >> 6;
  const int wr = wid >> 2, wcn = wid & 3;
  const int lr = lane & 15, hi = lane >> 4;
  int aoff[4][2], boff[4][2];
#pragma unroll
  for (int m = 0; m < 4; ++m) {
    int row = wr * 64 + m * 16 + lr;
#pragma unroll
    for (int k = 0; k < 2; ++k)
      aoff[m][k] = row * 128 + ((((k * 4 + hi)) ^ (row & 7)) << 4);
  }
#pragma unroll
  for (int n = 0; n < 4; ++n) {
    int row = wcn * 64 + n * 16 + lr;
#pragma unroll
    for (int k = 0; k < 2; ++k)
      boff[n][k] = 16384 + row * 128 + ((((k * 4 + hi)) ^ (row & 7)) << 4);
  }

  f32x4 acc[4][4];
#pragma unroll
  for (int m = 0; m < 4; ++m)
#pragma unroll
    for (int n = 0; n < 4; ++n) {
      f32x4 z = {0.f, 0.f, 0.f, 0.f};
      acc[m][n] = z;
    }

#define STG_A(c, t_) do {                                                   \
    const unsigned short* _s = Abase + (t_) * 64;                           \
    async_cp16(smem + (c) * 49152 + dstA, _s);                              \
    async_cp16(smem + (c) * 49152 + dstA + 8192, _s + 64 * 2048);           \
  } while (0)
#define STG_B(c, t_) do {                                                   \
    const unsigned short* _s = Bbase + (t_) * 64;                           \
    async_cp16(smem + (c) * 49152 + dstB, _s);                              \
    async_cp16(smem + (c) * 49152 + dstB + 8192, _s + 64 * 2048);           \
    async_cp16(smem + (c) * 49152 + dstB + 16384, _s + 128 * 2048);         \
    async_cp16(smem + (c) * 49152 + dstB + 24576, _s + 192 * 2048);         \
  } while (0)

  auto tile = [&](int T, int CC, bool DO_A, bool DO_B, int VM) __attribute__((always_inline)) {
    const char* Sb = smem + CC * 49152;
    bf16x8 a0[4], b0[4], a1[4], b1[4];
#pragma unroll
    for (int m = 0; m < 4; ++m) a0[m] = *(const bf16x8*)(Sb + aoff[m][0]);
#pragma unroll
    for (int n = 0; n < 4; ++n) b0[n] = *(const bf16x8*)(Sb + boff[n][0]);
    __builtin_amdgcn_sched_barrier(0);
#pragma unroll
    for (int m = 0; m < 4; ++m) a1[m] = *(const bf16x8*)(Sb + aoff[m][1]);
#pragma unroll
    for (int n = 0; n < 4; ++n) b1[n] = *(const bf16x8*)(Sb + boff[n][1]);
    if (DO_A) STG_A(CC ^ 1, T + 1);
    asm volatile("s_waitcnt lgkmcnt(8)" ::: "memory");
    __builtin_amdgcn_sched_barrier(0);
    __builtin_amdgcn_s_setprio(1);
#pragma unroll
    for (int m = 0; m < 4; ++m)
#pragma unroll
      for (int n = 0; n < 4; ++n)
        acc[m][n] = __builtin_amdgcn_mfma_f32_16x16x32_bf16(a0[m], b0[n], acc[m][n], 0, 0, 0);
    __builtin_amdgcn_s_setprio(0);
    __builtin_amdgcn_s_barrier();
    __builtin_amdgcn_sched_barrier(0);
    asm volatile("s_waitcnt lgkmcnt(0)" ::: "memory");
    __builtin_amdgcn_sched_barrier(0);
    if (DO_B) STG_B(CC, T + 2);
    __builtin_amdgcn_s_setprio(1);
#pragma unroll
    for (int m = 0; m < 4; ++m)
#pragma unroll
      for (int n = 0; n < 4; ++n)
        acc[m][n] = __builtin_amdgcn_mfma_f32_16x16x32_bf16(a1[m], b1[n], acc[m][n], 0, 0, 0);
    __builtin_amdgcn_s_setprio(0);
    if (VM == 0) asm volatile("s_waitcnt vmcnt(4)" ::: "memory");
    else if (VM == 1) asm volatile("s_waitcnt vmcnt(0)" ::: "memory");
    if (VM != 2) {
      __builtin_amdgcn_s_barrier();
      __builtin_amdgcn_sched_barrier(0);
    }
  };

  STG_B(0, 0);
  STG_A(0, 0);
  STG_B(1, 1);
  asm volatile("s_waitcnt vmcnt(4)" ::: "memory");
  __builtin_amdgcn_s_barrier();
  __builtin_amdgcn_sched_barrier(0);

  for (int it = 0; it < 15; ++it) {
    tile(2 * it, 0, true, true, 0);
    tile(2 * it + 1, 1, true, true, 0);
  }
  tile(30, 0, true, false, 1);
  tile(31, 1, false, false, 2);

  const int row_b = bm * 128 + wr * 64 + hi * 4;
  const int col_b = bn * 256 + wcn * 64 + lr;
#pragma unroll
  for (int m = 0; m < 4; ++m)
#pragma unroll
    for (int n = 0; n < 4; ++n) {
      int col = col_b + n * 16;
#pragma unroll
      for (int j = 0; j < 4; ++j) {
        int row = row_b + m * 16 + j;
        C0[(size_t)row * 2048 + col] = acc[m][n][j];
      }
    }
#undef STG_A
#undef STG_B
}

// ---------------- causal flash attention (swapped-QK, dual q-set) ----
// QBLK=128, 4 waves x 2 q-sets. Grid 512: block j (qt=15-ti) and j+256
// (qt=ti) are complementary -> uniform per-CU load; 2 blocks/CU -> 2 w/SIMD.
__global__ __launch_bounds__(256) void k_flash_attn(const unsigned short* __restrict__ Qg,
                                                    const unsigned short* __restrict__ Kg,
                                                    const unsigned short* __restrict__ Vg,
                                                    unsigned short* __restrict__ Og) {
  __shared__ unsigned short K_lds[2][64 * 128];   // [kv][dh], XOR-swizzled slots
  __shared__ unsigned short VT_lds[2][128 * 64];  // [dh][pos(kv)], XOR-swizzled

  const int bx = blockIdx.x;
  const int half = bx >> 8;
  const int j5 = bx & 255;
  const int ti = j5 >> 5;
  const int hb = j5 & 31;
  const int h = hb & 15, b = hb >> 4;
  const int qt = half ? ti : (15 - ti);

  const int t = threadIdx.x;
  const int lane = t & 63, wave = t >> 6;
  const int hi = lane >> 4, lr = lane & 15;

  const size_t head = (size_t)(b * NH + h) * (size_t)(S_LEN * DHD);
  const unsigned short* Q = Qg + head;
  const unsigned short* Kp = Kg + head;
  const unsigned short* Vp = Vg + head;

  const int kr0 = t >> 4;
  const int kgc = (t & 15) ^ (kr0 & 7);
  const unsigned short* Kbase = Kp + (size_t)kr0 * DHD + kgc * 8;
  const int kdst = t * 16;

  const int vdc = t & 15, vsp0 = t >> 4;
  const unsigned short* Vbase = Vp + (size_t)(2 * vsp0) * DHD + vdc * 8;
  const int bo0 = 16 * ((vsp0 >> 1) & 3) + 8 * ((vsp0 >> 3) & 1) + 4 * (vsp0 & 1);

  const float sc = 0.08838834764831845f;  // 1/sqrt(128)

  const int nt = 2 * (qt + 1);
  const int qb0 = qt * 128 + wave * 16;
  const int qb1 = qb0 + 64;

  bf16x8 qf0[4], qf1[4];
  {
    const unsigned short* qr0 = Q + (size_t)(qb0 + lr) * DHD;
    const unsigned short* qr1 = Q + (size_t)(qb1 + lr) * DHD;
#pragma unroll
    for (int kc = 0; kc < 4; ++kc) {
      qf0[kc] = *(const bf16x8*)(qr0 + kc * 32 + hi * 8);
      qf1[kc] = *(const bf16x8*)(qr1 + kc * 32 + hi * 8);
    }
  }

  f32x4 of0[8], of1[8];
#pragma unroll
  for (int i = 0; i < 8; ++i) {
    f32x4 z = {0.f, 0.f, 0.f, 0.f};
    of0[i] = z;
    of1[i] = z;
  }
  float mS0 = -INFINITY, mS1 = -INFINITY;
  float ls0 = 0.f, ls1 = 0.f;

  // prologue: stage tile 0 into buffer 0
  {
#pragma unroll
    for (int i = 0; i < 4; ++i)
      async_cp16((char*)K_lds[0] + kdst + i * 4096, Kbase + (size_t)(16 * i) * DHD);
    ushort8 va0 = *(const ushort8*)(Vbase);
    ushort8 vb0 = *(const ushort8*)(Vbase + DHD);
    ushort8 va1 = *(const ushort8*)(Vbase + (size_t)32 * DHD);
    ushort8 vb1 = *(const ushort8*)(Vbase + (size_t)33 * DHD);
#pragma unroll
    for (int j = 0; j < 8; ++j) {
      int row = vdc * 8 + j;
      int swz = ((j ^ vdc) & 7) << 4;
      *(unsigned int*)((char*)VT_lds[0] + row * 128 + (bo0 ^ swz)) =
          (unsigned int)va0[j] | ((unsigned int)vb0[j] << 16);
      *(unsigned int*)((char*)VT_lds[0] + row * 128 + ((bo0 | 64) ^ swz)) =
          (unsigned int)va1[j] | ((unsigned int)vb1[j] << 16);
    }
  }
  __syncthreads();

  for (int tt = 0; tt < nt; ++tt) {
    const int cur = tt & 1;
    const int kv0 = tt * 64;
    const bool more = (tt + 1 < nt);

    ushort8 va0, vb0, va1, vb1;
    if (more) {
      const unsigned short* ks = Kbase + (size_t)(kv0 + 64) * DHD;
#pragma unroll
      for (int i = 0; i < 4; ++i)
        async_cp16((char*)K_lds[cur ^ 1] + kdst + i * 4096, ks + (size_t)(16 * i) * DHD);
      const unsigned short* vs = Vbase + (size_t)(kv0 + 64) * DHD;
      va0 = *(const ushort8*)(vs);
      vb0 = *(const ushort8*)(vs + DHD);
      va1 = *(const ushort8*)(vs + (size_t)32 * DHD);
      vb1 = *(const ushort8*)(vs + (size_t)33 * DHD);
    }

    // QK^T swapped, both q-sets share each K fragment
    const char* Kb = (const char*)K_lds[cur];
    f32x4 sf0[4], sf1[4];
#pragma unroll
    for (int n = 0; n < 4; ++n) {
      f32x4 z = {0.f, 0.f, 0.f, 0.f};
      sf0[n] = z;
      sf1[n] = z;
    }
    __builtin_amdgcn_s_setprio(1);
#pragma unroll
    for (int n = 0; n < 4; ++n) {
      const int kr = n * 16 + lr;
      const int kswz = (kr & 7) << 4;
#pragma unroll
      for (int kc = 0; kc < 4; ++kc) {
        bf16x8 kf = *(const bf16x8*)(Kb + kr * 256 + ((kc * 64 + hi * 16) ^ kswz));
        sf0[n] = __builtin_amdgcn_mfma_f32_16x16x32_bf16(kf, qf0[kc], sf0[n], 0, 0, 0);
        sf1[n] = __builtin_amdgcn_mfma_f32_16x16x32_bf16(kf, qf1[kc], sf1[n], 0, 0, 0);
      }
    }
    __builtin_amdgcn_s_setprio(0);

    unsigned int pk0[4][2], pk1[4][2];
    float cb0[4], cb1[4];
    const bool act0 = kv0 <= qb0 + 15;
    const bool act1 = kv0 <= qb1 + 15;

#define SOFTMAX_SET(SF, MS, LS, PK, CB, QB, ACT) do {                        \
    if (ACT) {                                                               \
      float p_[4][4];                                                        \
      float mx = -INFINITY;                                                  \
      const int qrow_ = (QB) + lr;                                           \
      if (kv0 + 63 > (QB)) {                                                 \
        _Pragma("unroll")                                                    \
        for (int n = 0; n < 4; ++n)                                          \
          _Pragma("unroll")                                                  \
          for (int j = 0; j < 4; ++j) {                                      \
            int kvcol = kv0 + n * 16 + hi * 4 + j;                           \
            float v = (kvcol > qrow_) ? -INFINITY : SF[n][j];                \
            p_[n][j] = v;                                                    \
            mx = fmaxf(mx, v);                                               \
          }                                                                  \
      } else {                                                               \
        _Pragma("unroll")                                                    \
        for (int n = 0; n < 4; ++n)                                          \
          _Pragma("unroll")                                                  \
          for (int j = 0; j < 4; ++j) {                                      \
            float v = SF[n][j];                                              \
            p_[n][j] = v;                                                    \
            mx = fmaxf(mx, v);                                               \
          }                                                                  \
      }                                                                      \
      mx = fmaxf(mx, __shfl_xor(mx, 16));                                    \
      mx = fmaxf(mx, __shfl_xor(mx, 32));                                    \
      float mn = fmaxf(MS, mx);                                              \
      float corr = __expf((MS - mn) * sc);                                   \
      MS = mn;                                                               \
      float mns = mn * sc;                                                   \
      float rs = 0.f;                                                        \
      _Pragma("unroll")                                                      \
      for (int n = 0; n < 4; ++n)                                            \
        _Pragma("unroll")                                                    \
        for (int j = 0; j < 4; ++j) {                                        \
          float e = __expf(__builtin_fmaf(p_[n][j], sc, -mns));              \
          p_[n][j] = e;                                                      \
          rs += e;                                                           \
        }                                                                    \
      rs += __shfl_xor(rs, 16);                                              \
      rs += __shfl_xor(rs, 32);                                              \
      LS = LS * corr + rs;                                                   \
      _Pragma("unroll")                                                      \
      for (int n = 0; n < 4; ++n) {                                          \
        PK[n][0] = cvt_pk_bf16(p_[n][0], p_[n][1]);                          \
        PK[n][1] = cvt_pk_bf16(p_[n][2], p_[n][3]);                          \
      }                                                                      \
      _Pragma("unroll")                                                      \
      for (int j = 0; j < 4; ++j) CB[j] = __shfl(corr, hi * 4 + j);          \
    } else {                                                                 \
      _Pragma("unroll")                                                      \
      for (int n = 0; n < 4; ++n) { PK[n][0] = 0u; PK[n][1] = 0u; }          \
      _Pragma("unroll")                                                      \
      for (int j = 0; j < 4; ++j) CB[j] = 1.f;                               \
    }                                                                        \
  } while (0)

    SOFTMAX_SET(sf0, mS0, ls0, pk0, cb0, qb0, act0);
    SOFTMAX_SET(sf1, mS1, ls1, pk1, cb1, qb1, act1);
#undef SOFTMAX_SET

#pragma unroll
    for (int nd = 0; nd < 8; ++nd)
#pragma unroll
      for (int j = 0; j < 4; ++j) {
        of0[nd][j] *= cb0[j];
        of1[nd][j] *= cb1[j];
      }

    // PV: both q-sets share each V fragment
    const char* Vb = (const char*)VT_lds[cur];
    __builtin_amdgcn_s_setprio(1);
#pragma unroll
    for (int kc = 0; kc < 2; ++kc) {
      union { unsigned int u[4]; bf16x8 v; } pa0, pa1;
      pa0.u[0] = pk0[2 * kc][0];     pa0.u[1] = pk0[2 * kc][1];
      pa0.u[2] = pk0[2 * kc + 1][0]; pa0.u[3] = pk0[2 * kc + 1][1];
      pa1.u[0] = pk1[2 * kc][0];     pa1.u[1] = pk1[2 * kc][1];
      pa1.u[2] = pk1[2 * kc + 1][0]; pa1.u[3] = pk1[2 * kc + 1][1];
#pragma unroll
      for (int nd = 0; nd < 8; ++nd) {
        const int vr = nd * 16 + lr;
        const int vswz = ((vr & 7) ^ ((vr >> 3) & 7)) << 4;
        bf16x8 vf = *(const bf16x8*)(Vb + vr * 128 + ((kc * 64 + hi * 16) ^ vswz));
        of0[nd] = __builtin_amdgcn_mfma_f32_16x16x32_bf16(pa0.v, vf, of0[nd], 0, 0, 0);
        of1[nd] = __builtin_amdgcn_mfma_f32_16x16x32_bf16(pa1.v, vf, of1[nd], 0, 0, 0);
      }
    }
    __builtin_amdgcn_s_setprio(0);

    if (more) {
      char* Vw = (char*)VT_lds[cur ^ 1];
#pragma unroll
      for (int j = 0; j < 8; ++j) {
        int row = vdc * 8 + j;
        int swz = ((j ^ vdc) & 7) << 4;
        *(unsigned int*)(Vw + row * 128 + (bo0 ^ swz)) =
            (unsigned int)va0[j] | ((unsigned int)vb0[j] << 16);
        *(unsigned int*)(Vw + row * 128 + ((bo0 | 64) ^ swz)) =
            (unsigned int)va1[j] | ((unsigned int)vb1[j] << 16);
      }
    }
    __syncthreads();
  }

  // epilogue: normalize, write [B][S][H][DH], both sets
  float inv0[4], inv1[4];
#pragma unroll
  for (int j = 0; j < 4; ++j) {
    inv0[j] = 1.0f / __shfl(ls0, hi * 4 + j);
    inv1[j] = 1.0f / __shfl(ls1, hi * 4 + j);
  }
#pragma unroll
  for (int nd = 0; nd < 8; ++nd)
#pragma unroll
    for (int j = 0; j < 4; ++j) {
      int qr0 = qb0 + hi * 4 + j;
      int qr1 = qb1 + hi * 4 + j;
      Og[((size_t)(b * S_LEN + qr0) * NH + h) * DHD + nd * 16 + lr] = f2bf(of0[nd][j] * inv0[j]);
      Og[((size_t)(b * S_LEN + qr1) * NH + h) * DHD + nd * 16 + lr] = f2bf(of1[nd][j] * inv1[j]);
    }
}

// ---------------- launch ----------------
extern "C" void kernel_launch(void* const* d_in, const int* in_sizes, int n_in,
                              void* d_out, int out_size, void* d_ws, size_t ws_size,
                              hipStream_t stream) {
  const float* x  = (const float*)d_in[0];
  const float* wq = (const float*)d_in[1];
  const float* wk = (const float*)d_in[2];
  const float* wv = (const float*)d_in[3];
  const float* wo = (const float*)d_in[4];
  float* out = (float*)d_out;

  char* ws = (char*)d_ws;
  unsigned short* xb    = (unsigned short*)(ws);              // 16 MB (reused as attn out)
  unsigned short* wqT   = (unsigned short*)(ws + 16777216);   // 8 MB each, contiguous -> [6144][2048]
  unsigned short* woT   = (unsigned short*)(ws + 41943040);
  unsigned short* qb    = (unsigned short*)(ws + 50331648);   // 16 MB each
  unsigned short* kb    = (unsigned short*)(ws + 67108864);
  unsigned short* vb    = (unsigned short*)(ws + 83886080);
  float*          cosT  = (float*)(ws + 100663296);           // 512 KB
  float*          sinT  = (float*)(ws + 101187584);
  unsigned short* attnb = xb;

  k_cast_bf16<<<8192, 256, 0, stream>>>(x, xb, 2097152);
  dim3 tg(32, 32, 4);
  k_transpose_all<<<tg, 256, 0, stream>>>(wq, wk, wv, wo, wqT);
  k_rope_table<<<512, 256, 0, stream>>>(cosT, sinT);

  // fused q/k/v projection: 16x24 tiles of 256x256 -> 384 blocks
  k_gemm256<<<384, 512, 0, stream>>>(xb, wqT, qb, kb, vb, cosT, sinT);

  // attention: 512 blocks (16 q-tiles x 32 hb), heavy/light complementary halves
  k_flash_attn<<<512, 256, 0, stream>>>(qb, kb, vb, attnb);

  // output projection: 32x8 tiles of 128x256 -> 256 blocks (1 round)
  k_gemm128<<<256, 512, 0, stream>>>(attnb, woT, out, 2);
}

// Round 8
// 278.785 us; speedup vs baseline: 1.0297x; 1.0297x over previous
//
#include <hip/hip_runtime.h>
#include <hip/hip_bf16.h>
#include <stdint.h>

#define B_SZ   2
#define S_LEN  2048
#define DMODEL 2048
#define NH     16
#define DHD    128

typedef __attribute__((ext_vector_type(8))) __bf16 bf16x8;
typedef __attribute__((ext_vector_type(4))) float  f32x4;
typedef __attribute__((ext_vector_type(4))) float  float4v;
typedef __attribute__((ext_vector_type(8))) unsigned short ushort8;
typedef __attribute__((ext_vector_type(4))) unsigned short ushort4v;

__device__ __forceinline__ unsigned short f2bf(float f) {
  unsigned int u = __float_as_uint(f);
  unsigned int r = (u + 0x7fffu + ((u >> 16) & 1u)) >> 16;
  return (unsigned short)r;
}

__device__ __forceinline__ unsigned int cvt_pk_bf16(float lo, float hi) {
  unsigned int r;
  asm("v_cvt_pk_bf16_f32 %0, %1, %2" : "=v"(r) : "v"(lo), "v"(hi));
  return r;
}

__device__ __forceinline__ void async_cp16(void* lds, const void* g) {
  __builtin_amdgcn_global_load_lds(
      (const __attribute__((address_space(1))) void*)g,
      (__attribute__((address_space(3))) void*)lds, 16, 0, 0);
}

// ------- merged prep: cast x -> bf16 (blocks 0..8191) + rope table (8192..8703) -------
__global__ __launch_bounds__(256) void k_prep(const float* __restrict__ in,
                                              unsigned short* __restrict__ out,
                                              float* __restrict__ cosT,
                                              float* __restrict__ sinT) {
  const int bx = blockIdx.x;
  const int t = threadIdx.x;
  if (bx < 8192) {
    int i = bx * 256 + t;  // < 2097152 exactly
    float4v v = ((const float4v*)in)[i];
    ushort4v o;
    o[0] = f2bf(v[0]); o[1] = f2bf(v[1]); o[2] = f2bf(v[2]); o[3] = f2bf(v[3]);
    ((ushort4v*)out)[i] = o;
  } else {
    int i = (bx - 8192) * 256 + t;  // < S_LEN*64
    int s = i >> 6, dj = i & 63;
    float e = __expf(-9.210340371976184f * (float)dj * (1.0f / 64.0f));  // 10000^{-dj/64}
    float f = (float)s * e;
    cosT[i] = cosf(f);
    sinT[i] = sinf(f);
  }
}

// ---- transpose + cast all four weights: W[K][N] -> WT[N][K] bf16 (z-batched) ----
__global__ __launch_bounds__(256) void k_transpose_all(const float* __restrict__ w0,
                                                       const float* __restrict__ w1,
                                                       const float* __restrict__ w2,
                                                       const float* __restrict__ w3,
                                                       unsigned short* __restrict__ WTbase) {
  __shared__ unsigned short tile[64 * 72];
  const int z = blockIdx.z;
  const float* W = (z == 0) ? w0 : (z == 1) ? w1 : (z == 2) ? w2 : w3;
  unsigned short* WT = WTbase + (size_t)z * 4194304;
  const int n0 = blockIdx.x * 64;
  const int k0 = blockIdx.y * 64;
  const int t = threadIdx.x;
#pragma unroll
  for (int i = 0; i < 4; ++i) {
    int c = t + 256 * i;
    int r = c >> 4, c4 = c & 15;
    float4v v = *(const float4v*)(W + (size_t)(k0 + r) * DMODEL + n0 + c4 * 4);
    ushort4v o;
    o[0] = f2bf(v[0]); o[1] = f2bf(v[1]); o[2] = f2bf(v[2]); o[3] = f2bf(v[3]);
    *(ushort4v*)(&tile[r * 72 + c4 * 4]) = o;
  }
  __syncthreads();
#pragma unroll
  for (int i = 0; i < 2; ++i) {
    int c = t + 256 * i;
    int n = c >> 3, k8 = c & 7;
    ushort8 o;
#pragma unroll
    for (int j = 0; j < 8; ++j) o[j] = tile[(k8 * 8 + j) * 72 + n];
    *(ushort8*)(WT + (size_t)(n0 + n) * DMODEL + k0 + k8 * 8) = o;
  }
}

// ---------------- 128x256x64 2-phase look-ahead GEMM (R6 body, 112.0 us) ----
// Per tile: p0 reads k0 frags, MFMA n{0,1}, issues k1 reads mid-cluster
// (overlap with MFMA n{2,3}); mid barrier; p1 zero-read, stages B(t+2), vmcnt(4).
// EPI 0: fp32 row-major.  EPI 1: fused QKV epilogue (RoPE on q/k), bf16 BHSD.
template <int EPI>
__global__ __launch_bounds__(512, 2) void k_gemm128(
    const unsigned short* __restrict__ A,
    const unsigned short* __restrict__ BT,
    float* __restrict__ C0,
    unsigned short* __restrict__ Cq,
    unsigned short* __restrict__ Ck,
    unsigned short* __restrict__ Cv,
    const float* __restrict__ cosT,
    const float* __restrict__ sinT,
    int chn) {
  __shared__ char smem[98304];
  const int tid = threadIdx.x;

  // 2-D XCD chunk swizzle: 8 XCDs as 2 (bm) x 4 (bn); chunk = 16bm x chn bn
  const int xcd = blockIdx.x & 7;
  const int idx = blockIdx.x >> 3;
  const int bm = (xcd >> 2) * 16 + (idx & 15);
  const int bn = (xcd & 3) * chn + (idx >> 4);

  const int gs = (tid & 7) ^ ((tid >> 3) & 7);
  const unsigned short* Abase = A + (size_t)(bm * 128 + (tid >> 3)) * 2048 + gs * 8;
  const unsigned short* Bbase = BT + (size_t)(bn * 256 + (tid >> 3)) * 2048 + gs * 8;
  const int dstA = tid * 16;
  const int dstB = 16384 + tid * 16;

  const int lane = tid & 63, wid = tid >> 6;
  const int wr = wid >> 2, wcn = wid & 3;
  const int lr = lane & 15, hi = lane >> 4;
  int aoff[4][2], boff[4][2];
#pragma unroll
  for (int m = 0; m < 4; ++m) {
    int row = wr * 64 + m * 16 + lr;
#pragma unroll
    for (int k = 0; k < 2; ++k)
      aoff[m][k] = row * 128 + ((((k * 4 + hi)) ^ (row & 7)) << 4);
  }
#pragma unroll
  for (int n = 0; n < 4; ++n) {
    int row = wcn * 64 + n * 16 + lr;
#pragma unroll
    for (int k = 0; k < 2; ++k)
      boff[n][k] = 16384 + row * 128 + ((((k * 4 + hi)) ^ (row & 7)) << 4);
  }

  f32x4 acc[4][4];
#pragma unroll
  for (int m = 0; m < 4; ++m)
#pragma unroll
    for (int n = 0; n < 4; ++n) {
      f32x4 z = {0.f, 0.f, 0.f, 0.f};
      acc[m][n] = z;
    }

#define STG_A(c, t_) do {                                                   \
    const unsigned short* _s = Abase + (t_) * 64;                           \
    async_cp16(smem + (c) * 49152 + dstA, _s);                              \
    async_cp16(smem + (c) * 49152 + dstA + 8192, _s + 64 * 2048);           \
  } while (0)
#define STG_B(c, t_) do {                                                   \
    const unsigned short* _s = Bbase + (t_) * 64;                           \
    async_cp16(smem + (c) * 49152 + dstB, _s);                              \
    async_cp16(smem + (c) * 49152 + dstB + 8192, _s + 64 * 2048);           \
    async_cp16(smem + (c) * 49152 + dstB + 16384, _s + 128 * 2048);         \
    async_cp16(smem + (c) * 49152 + dstB + 24576, _s + 192 * 2048);         \
  } while (0)

  auto tile = [&](int T, int CC, bool DO_A, bool DO_B, int VM) __attribute__((always_inline)) {
    const char* Sb = smem + CC * 49152;
    bf16x8 a0[4], b0[4], a1[4], b1[4];
#pragma unroll
    for (int m = 0; m < 4; ++m) a0[m] = *(const bf16x8*)(Sb + aoff[m][0]);
#pragma unroll
    for (int n = 0; n < 4; ++n) b0[n] = *(const bf16x8*)(Sb + boff[n][0]);
    if (DO_A) STG_A(CC ^ 1, T + 1);
    asm volatile("s_waitcnt lgkmcnt(0)" ::: "memory");
    __builtin_amdgcn_sched_barrier(0);
    __builtin_amdgcn_s_setprio(1);
#pragma unroll
    for (int m = 0; m < 4; ++m) {
      acc[m][0] = __builtin_amdgcn_mfma_f32_16x16x32_bf16(a0[m], b0[0], acc[m][0], 0, 0, 0);
      acc[m][1] = __builtin_amdgcn_mfma_f32_16x16x32_bf16(a0[m], b0[1], acc[m][1], 0, 0, 0);
    }
    __builtin_amdgcn_s_setprio(0);
    __builtin_amdgcn_sched_barrier(0);
    // k1 reads issue here, hidden under the second MFMA half
#pragma unroll
    for (int m = 0; m < 4; ++m) a1[m] = *(const bf16x8*)(Sb + aoff[m][1]);
#pragma unroll
    for (int n = 0; n < 4; ++n) b1[n] = *(const bf16x8*)(Sb + boff[n][1]);
    __builtin_amdgcn_sched_barrier(0);
    __builtin_amdgcn_s_setprio(1);
#pragma unroll
    for (int m = 0; m < 4; ++m) {
      acc[m][2] = __builtin_amdgcn_mfma_f32_16x16x32_bf16(a0[m], b0[2], acc[m][2], 0, 0, 0);
      acc[m][3] = __builtin_amdgcn_mfma_f32_16x16x32_bf16(a0[m], b0[3], acc[m][3], 0, 0, 0);
    }
    __builtin_amdgcn_s_setprio(0);
    __builtin_amdgcn_s_barrier();
    __builtin_amdgcn_sched_barrier(0);
    asm volatile("s_waitcnt lgkmcnt(0)" ::: "memory");
    __builtin_amdgcn_sched_barrier(0);
    if (DO_B) STG_B(CC, T + 2);
    __builtin_amdgcn_s_setprio(1);
#pragma unroll
    for (int m = 0; m < 4; ++m)
#pragma unroll
      for (int n = 0; n < 4; ++n)
        acc[m][n] = __builtin_amdgcn_mfma_f32_16x16x32_bf16(a1[m], b1[n], acc[m][n], 0, 0, 0);
    __builtin_amdgcn_s_setprio(0);
    if (VM == 0) asm volatile("s_waitcnt vmcnt(4)" ::: "memory");
    else if (VM == 1) asm volatile("s_waitcnt vmcnt(0)" ::: "memory");
    if (VM != 2) {
      __builtin_amdgcn_s_barrier();
      __builtin_amdgcn_sched_barrier(0);
    }
  };

  STG_B(0, 0);
  STG_A(0, 0);
  STG_B(1, 1);
  asm volatile("s_waitcnt vmcnt(4)" ::: "memory");
  __builtin_amdgcn_s_barrier();
  __builtin_amdgcn_sched_barrier(0);

  for (int it = 0; it < 15; ++it) {
    tile(2 * it, 0, true, true, 0);
    tile(2 * it + 1, 1, true, true, 0);
  }
  tile(30, 0, true, false, 1);
  tile(31, 1, false, false, 2);

  // ---- epilogue ----
  const int row_b = bm * 128 + wr * 64 + hi * 4;
  const int col_b = bn * 256 + wcn * 64 + lr;
  if (EPI == 0) {
#pragma unroll
    for (int m = 0; m < 4; ++m)
#pragma unroll
      for (int n = 0; n < 4; ++n) {
        int col = col_b + n * 16;
#pragma unroll
        for (int j = 0; j < 4; ++j) {
          int row = row_b + m * 16 + j;
          C0[(size_t)row * 2048 + col] = acc[m][n][j];
        }
      }
  } else {
    const int sel = bn >> 3;  // 0:q 1:k 2:v (2048-wide each)
#pragma unroll
    for (int m = 0; m < 4; ++m) {
#pragma unroll
      for (int n = 0; n < 4; ++n) {
        int col = col_b + n * 16;
        int hh = (col >> 7) & 15, d = col & 127;
        if (sel == 2) {
#pragma unroll
          for (int j = 0; j < 4; ++j) {
            int row = row_b + m * 16 + j;
            int b = row >> 11, s = row & 2047;
            Cv[((size_t)(b * NH + hh) * S_LEN + s) * DHD + d] = f2bf(acc[m][n][j]);
          }
        } else {
          unsigned short* dst = sel ? Ck : Cq;
          int dj = d >> 1;
          float sgn = (d & 1) ? 1.f : -1.f;
#pragma unroll
          for (int j = 0; j < 4; ++j) {
            int row = row_b + m * 16 + j;
            int b = row >> 11, s = row & 2047;
            float v = acc[m][n][j];
            float pp = __shfl_xor(v, 1);
            float cc = cosT[(s << 6) + dj];
            float sn = sinT[(s << 6) + dj];
            dst[((size_t)(b * NH + hh) * S_LEN + s) * DHD + d] = f2bf(v * cc + sgn * pp * sn);
          }
        }
      }
    }
  }
#undef STG_A
#undef STG_B
}

// ---------------- causal flash attention (R5 structure + defer-max) ----
// Q,K,V: [B][H][S][DH] bf16.  O: [B][S][H][DH] bf16.
// Swapped QK^T (lane holds one q-row), kv-permuted V, triangle-paired passes.
__global__ __launch_bounds__(256) void k_flash_attn(const unsigned short* __restrict__ Qg,
                                                    const unsigned short* __restrict__ Kg,
                                                    const unsigned short* __restrict__ Vg,
                                                    unsigned short* __restrict__ Og) {
  __shared__ unsigned short K_lds[2][64 * 128];   // [kv][dh], XOR-swizzled slots
  __shared__ unsigned short VT_lds[2][128 * 64];  // [dh][pos(kv)], XOR-swizzled

  const int pq = blockIdx.x, h = blockIdx.y, b = blockIdx.z;
  const int t = threadIdx.x;
  const int lane = t & 63, wave = t >> 6;
  const int hi = lane >> 4, lr = lane & 15;

  const size_t head = (size_t)(b * NH + h) * (size_t)(S_LEN * DHD);
  const unsigned short* Q = Qg + head;
  const unsigned short* Kp = Kg + head;
  const unsigned short* Vp = Vg + head;

  const int kr0 = t >> 4;
  const int kgc = (t & 15) ^ (kr0 & 7);
  const unsigned short* Kbase = Kp + (size_t)kr0 * DHD + kgc * 8;
  const int kdst = t * 16;

  const int vdc = t & 15, vsp0 = t >> 4;
  const unsigned short* Vbase = Vp + (size_t)(2 * vsp0) * DHD + vdc * 8;
  const int bo0 = 16 * ((vsp0 >> 1) & 3) + 8 * ((vsp0 >> 3) & 1) + 4 * (vsp0 & 1);

  const float sc = 0.08838834764831845f;  // 1/sqrt(128)

  for (int pass = 0; pass < 2; ++pass) {
    const int qt = (pass == 0) ? pq : (31 - pq);
    const int nt = qt + 1;
    const int qbase = qt * 64 + wave * 16;
    const int qrow = qbase + lr;

    bf16x8 qf[4];
    {
      const unsigned short* qr_ = Q + (size_t)(qbase + lr) * DHD;
#pragma unroll
      for (int kc = 0; kc < 4; ++kc) qf[kc] = *(const bf16x8*)(qr_ + kc * 32 + hi * 8);
    }

    f32x4 of[8];
#pragma unroll
    for (int i = 0; i < 8; ++i) {
      f32x4 z = {0.f, 0.f, 0.f, 0.f};
      of[i] = z;
    }
    float mS = -INFINITY;
    float lsum = 0.f;

    // prologue: stage tile 0 into buffer 0
    {
#pragma unroll
      for (int i = 0; i < 4; ++i)
        async_cp16((char*)K_lds[0] + kdst + i * 4096, Kbase + (size_t)(16 * i) * DHD);
      ushort8 va0 = *(const ushort8*)(Vbase);
      ushort8 vb0 = *(const ushort8*)(Vbase + DHD);
      ushort8 va1 = *(const ushort8*)(Vbase + (size_t)32 * DHD);
      ushort8 vb1 = *(const ushort8*)(Vbase + (size_t)33 * DHD);
#pragma unroll
      for (int j = 0; j < 8; ++j) {
        int row = vdc * 8 + j;
        int swz = ((j ^ vdc) & 7) << 4;
        *(unsigned int*)((char*)VT_lds[0] + row * 128 + (bo0 ^ swz)) =
            (unsigned int)va0[j] | ((unsigned int)vb0[j] << 16);
        *(unsigned int*)((char*)VT_lds[0] + row * 128 + ((bo0 | 64) ^ swz)) =
            (unsigned int)va1[j] | ((unsigned int)vb1[j] << 16);
      }
    }
    __syncthreads();

    for (int tt = 0; tt < nt; ++tt) {
      const int cur = tt & 1;
      const int kv0 = tt * 64;
      const bool more = (tt + 1 < nt);
      const bool diag = (tt == qt);

      // issue next tile's loads (K async->LDS, V->regs)
      ushort8 va0, vb0, va1, vb1;
      if (more) {
        const unsigned short* ks = Kbase + (size_t)(kv0 + 64) * DHD;
#pragma unroll
        for (int i = 0; i < 4; ++i)
          async_cp16((char*)K_lds[cur ^ 1] + kdst + i * 4096, ks + (size_t)(16 * i) * DHD);
        const unsigned short* vs = Vbase + (size_t)(kv0 + 64) * DHD;
        va0 = *(const ushort8*)(vs);
        vb0 = *(const ushort8*)(vs + DHD);
        va1 = *(const ushort8*)(vs + (size_t)32 * DHD);
        vb1 = *(const ushort8*)(vs + (size_t)33 * DHD);
      }

      // QK^T swapped: lane q=lr, kv=kv0+16n+4*hi+reg
      const char* Kb = (const char*)K_lds[cur];
      f32x4 sf[4];
#pragma unroll
      for (int n = 0; n < 4; ++n) {
        f32x4 z = {0.f, 0.f, 0.f, 0.f};
        sf[n] = z;
      }
      __builtin_amdgcn_s_setprio(1);
#pragma unroll
      for (int n = 0; n < 4; ++n) {
        const int kr = n * 16 + lr;
        const int kswz = (kr & 7) << 4;
#pragma unroll
        for (int kc = 0; kc < 4; ++kc) {
          bf16x8 kf = *(const bf16x8*)(Kb + kr * 256 + ((kc * 64 + hi * 16) ^ kswz));
          sf[n] = __builtin_amdgcn_mfma_f32_16x16x32_bf16(kf, qf[kc], sf[n], 0, 0, 0);
        }
      }
      __builtin_amdgcn_s_setprio(0);

      // in-register masked online softmax (per-lane q-row) with defer-max
      float p[4][4];
      float mx = -INFINITY;
      if (diag) {
#pragma unroll
        for (int n = 0; n < 4; ++n)
#pragma unroll
          for (int j = 0; j < 4; ++j) {
            int kvcol = kv0 + n * 16 + hi * 4 + j;
            float v = (kvcol > qrow) ? -INFINITY : sf[n][j];
            p[n][j] = v;
            mx = fmaxf(mx, v);
          }
      } else {
#pragma unroll
        for (int n = 0; n < 4; ++n)
#pragma unroll
          for (int j = 0; j < 4; ++j) {
            float v = sf[n][j];
            p[n][j] = v;
            mx = fmaxf(mx, v);
          }
      }
      mx = fmaxf(mx, __shfl_xor(mx, 16));
      mx = fmaxf(mx, __shfl_xor(mx, 32));
      // defer-max (T13): skip rescale when tile max growth (scaled) <= 8
      const bool nore = __all((mx - mS) * sc <= 8.f);
      float mn, corr;
      if (nore) {
        mn = mS;
        corr = 1.f;
      } else {
        mn = fmaxf(mS, mx);
        corr = __expf((mS - mn) * sc);
      }
      mS = mn;
      float mns = mn * sc;
      float rs = 0.f;
#pragma unroll
      for (int n = 0; n < 4; ++n)
#pragma unroll
        for (int j = 0; j < 4; ++j) {
          float e = __expf(__builtin_fmaf(p[n][j], sc, -mns));
          p[n][j] = e;
          rs += e;
        }
      rs += __shfl_xor(rs, 16);
      rs += __shfl_xor(rs, 32);
      lsum = lsum * corr + rs;

      // pack P to bf16 (lane-local; feeds PV A-operand directly)
      unsigned int pk[4][2];
#pragma unroll
      for (int n = 0; n < 4; ++n) {
        pk[n][0] = cvt_pk_bf16(p[n][0], p[n][1]);
        pk[n][1] = cvt_pk_bf16(p[n][2], p[n][3]);
      }

      // rescale O only when the running max moved (wave-uniform skip)
      if (!nore) {
        float corrb[4];
#pragma unroll
        for (int j = 0; j < 4; ++j) corrb[j] = __shfl(corr, hi * 4 + j);
#pragma unroll
        for (int nd = 0; nd < 8; ++nd)
#pragma unroll
          for (int j = 0; j < 4; ++j) of[nd][j] *= corrb[j];
      }

      // PV: O[16 q][128 dh] += P * V (V stored kv-permuted, A is lane-local)
      const char* Vb = (const char*)VT_lds[cur];
      __builtin_amdgcn_s_setprio(1);
#pragma unroll
      for (int kc = 0; kc < 2; ++kc) {
        union { unsigned int u[4]; bf16x8 v; } pa;
        pa.u[0] = pk[2 * kc][0];
        pa.u[1] = pk[2 * kc][1];
        pa.u[2] = pk[2 * kc + 1][0];
        pa.u[3] = pk[2 * kc + 1][1];
#pragma unroll
        for (int nd = 0; nd < 8; ++nd) {
          const int vr = nd * 16 + lr;
          const int vswz = ((vr & 7) ^ ((vr >> 3) & 7)) << 4;
          bf16x8 vf = *(const bf16x8*)(Vb + vr * 128 + ((kc * 64 + hi * 16) ^ vswz));
          of[nd] = __builtin_amdgcn_mfma_f32_16x16x32_bf16(pa.v, vf, of[nd], 0, 0, 0);
        }
      }
      __builtin_amdgcn_s_setprio(0);

      // complete next tile's V staging (reg -> LDS, permuted+swizzled)
      if (more) {
        char* Vw = (char*)VT_lds[cur ^ 1];
#pragma unroll
        for (int j = 0; j < 8; ++j) {
          int row = vdc * 8 + j;
          int swz = ((j ^ vdc) & 7) << 4;
          *(unsigned int*)(Vw + row * 128 + (bo0 ^ swz)) =
              (unsigned int)va0[j] | ((unsigned int)vb0[j] << 16);
          *(unsigned int*)(Vw + row * 128 + ((bo0 | 64) ^ swz)) =
              (unsigned int)va1[j] | ((unsigned int)vb1[j] << 16);
        }
      }
      __syncthreads();
    }

    // epilogue: normalize, write [B][S][H][DH]
    float inv[4];
#pragma unroll
    for (int j = 0; j < 4; ++j) {
      float ls = __shfl(lsum, hi * 4 + j);
      inv[j] = 1.0f / ls;
    }
#pragma unroll
    for (int nd = 0; nd < 8; ++nd)
#pragma unroll
      for (int j = 0; j < 4; ++j) {
        int qr = qbase + hi * 4 + j;
        Og[((size_t)(b * S_LEN + qr) * NH + h) * DHD + nd * 16 + lr] = f2bf(of[nd][j] * inv[j]);
      }
  }
}

// ---------------- launch ----------------
extern "C" void kernel_launch(void* const* d_in, const int* in_sizes, int n_in,
                              void* d_out, int out_size, void* d_ws, size_t ws_size,
                              hipStream_t stream) {
  const float* x  = (const float*)d_in[0];
  const float* wq = (const float*)d_in[1];
  const float* wk = (const float*)d_in[2];
  const float* wv = (const float*)d_in[3];
  const float* wo = (const float*)d_in[4];
  float* out = (float*)d_out;

  char* ws = (char*)d_ws;
  unsigned short* xb    = (unsigned short*)(ws);              // 16 MB (reused as attn out)
  unsigned short* wqT   = (unsigned short*)(ws + 16777216);   // 8 MB each, contiguous -> [6144][2048]
  unsigned short* woT   = (unsigned short*)(ws + 41943040);
  unsigned short* qb    = (unsigned short*)(ws + 50331648);   // 16 MB each
  unsigned short* kb    = (unsigned short*)(ws + 67108864);
  unsigned short* vb    = (unsigned short*)(ws + 83886080);
  float*          cosT  = (float*)(ws + 100663296);           // 512 KB
  float*          sinT  = (float*)(ws + 101187584);
  unsigned short* attnb = xb;

  k_prep<<<8704, 256, 0, stream>>>(x, xb, cosT, sinT);
  dim3 tg(32, 32, 4);
  k_transpose_all<<<tg, 256, 0, stream>>>(wq, wk, wv, wo, wqT);

  // fused q/k/v projection: 32x24 tiles of 128x256 -> 768 blocks (3 even rounds)
  k_gemm128<1><<<768, 512, 0, stream>>>(xb, wqT, nullptr, qb, kb, vb, cosT, sinT, 6);

  // attention: 16 q-tile pairs (triangle pairing), 16 heads, batch 2 -> 512 blocks
  dim3 ga(16, 16, 2);
  k_flash_attn<<<ga, 256, 0, stream>>>(qb, kb, vb, attnb);

  // output projection: 32x8 tiles -> 256 blocks (1 round)
  k_gemm128<0><<<256, 512, 0, stream>>>(attnb, woT, out, nullptr, nullptr, nullptr,
                                        nullptr, nullptr, 2);
}

// Round 9
// 229.111 us; speedup vs baseline: 1.2530x; 1.2168x over previous
//
#include <hip/hip_runtime.h>
#include <hip/hip_bf16.h>
#include <stdint.h>

#define B_SZ   2
#define S_LEN  2048
#define DMODEL 2048
#define NH     16
#define DHD    128

typedef __attribute__((ext_vector_type(8))) __bf16 bf16x8;
typedef __attribute__((ext_vector_type(4))) float  f32x4;
typedef __attribute__((ext_vector_type(4))) float  float4v;
typedef __attribute__((ext_vector_type(8))) unsigned short ushort8;
typedef __attribute__((ext_vector_type(4))) unsigned short ushort4v;

__device__ __forceinline__ unsigned short f2bf(float f) {
  unsigned int u = __float_as_uint(f);
  unsigned int r = (u + 0x7fffu + ((u >> 16) & 1u)) >> 16;
  return (unsigned short)r;
}

__device__ __forceinline__ unsigned int cvt_pk_bf16(float lo, float hi) {
  unsigned int r;
  asm("v_cvt_pk_bf16_f32 %0, %1, %2" : "=v"(r) : "v"(lo), "v"(hi));
  return r;
}

__device__ __forceinline__ void async_cp16(void* lds, const void* g) {
  __builtin_amdgcn_global_load_lds(
      (const __attribute__((address_space(1))) void*)g,
      (__attribute__((address_space(3))) void*)lds, 16, 0, 0);
}

// ------- merged prep: cast x -> bf16 (blocks 0..8191) + rope table (8192..8703) -------
__global__ __launch_bounds__(256) void k_prep(const float* __restrict__ in,
                                              unsigned short* __restrict__ out,
                                              float* __restrict__ cosT,
                                              float* __restrict__ sinT) {
  const int bx = blockIdx.x;
  const int t = threadIdx.x;
  if (bx < 8192) {
    int i = bx * 256 + t;  // < 2097152 exactly
    float4v v = ((const float4v*)in)[i];
    ushort4v o;
    o[0] = f2bf(v[0]); o[1] = f2bf(v[1]); o[2] = f2bf(v[2]); o[3] = f2bf(v[3]);
    ((ushort4v*)out)[i] = o;
  } else {
    int i = (bx - 8192) * 256 + t;  // < S_LEN*64
    int s = i >> 6, dj = i & 63;
    float e = __expf(-9.210340371976184f * (float)dj * (1.0f / 64.0f));  // 10000^{-dj/64}
    float f = (float)s * e;
    cosT[i] = cosf(f);
    sinT[i] = sinf(f);
  }
}

// ---- transpose + cast all four weights: W[K][N] -> WT[N][K] bf16 (z-batched) ----
__global__ __launch_bounds__(256) void k_transpose_all(const float* __restrict__ w0,
                                                       const float* __restrict__ w1,
                                                       const float* __restrict__ w2,
                                                       const float* __restrict__ w3,
                                                       unsigned short* __restrict__ WTbase) {
  __shared__ unsigned short tile[64 * 72];
  const int z = blockIdx.z;
  const float* W = (z == 0) ? w0 : (z == 1) ? w1 : (z == 2) ? w2 : w3;
  unsigned short* WT = WTbase + (size_t)z * 4194304;
  const int n0 = blockIdx.x * 64;
  const int k0 = blockIdx.y * 64;
  const int t = threadIdx.x;
#pragma unroll
  for (int i = 0; i < 4; ++i) {
    int c = t + 256 * i;
    int r = c >> 4, c4 = c & 15;
    float4v v = *(const float4v*)(W + (size_t)(k0 + r) * DMODEL + n0 + c4 * 4);
    ushort4v o;
    o[0] = f2bf(v[0]); o[1] = f2bf(v[1]); o[2] = f2bf(v[2]); o[3] = f2bf(v[3]);
    *(ushort4v*)(&tile[r * 72 + c4 * 4]) = o;
  }
  __syncthreads();
#pragma unroll
  for (int i = 0; i < 2; ++i) {
    int c = t + 256 * i;
    int n = c >> 3, k8 = c & 7;
    ushort8 o;
#pragma unroll
    for (int j = 0; j < 8; ++j) o[j] = tile[(k8 * 8 + j) * 72 + n];
    *(ushort8*)(WT + (size_t)(n0 + n) * DMODEL + k0 + k8 * 8) = o;
  }
}

// ---------------- 128x256x64 2-phase look-ahead GEMM (R6 body) ----
// EPI 0: fp32 row-major.  EPI 1: fused QKV epilogue (RoPE on q/k), bf16 BHSD.
template <int EPI>
__global__ __launch_bounds__(512, 2) void k_gemm128(
    const unsigned short* __restrict__ A,
    const unsigned short* __restrict__ BT,
    float* __restrict__ C0,
    unsigned short* __restrict__ Cq,
    unsigned short* __restrict__ Ck,
    unsigned short* __restrict__ Cv,
    const float* __restrict__ cosT,
    const float* __restrict__ sinT,
    int chn) {
  __shared__ char smem[98304];
  const int tid = threadIdx.x;

  // 2-D XCD chunk swizzle: 8 XCDs as 2 (bm) x 4 (bn); chunk = 16bm x chn bn
  const int xcd = blockIdx.x & 7;
  const int idx = blockIdx.x >> 3;
  const int bm = (xcd >> 2) * 16 + (idx & 15);
  const int bn = (xcd & 3) * chn + (idx >> 4);

  const int gs = (tid & 7) ^ ((tid >> 3) & 7);
  const unsigned short* Abase = A + (size_t)(bm * 128 + (tid >> 3)) * 2048 + gs * 8;
  const unsigned short* Bbase = BT + (size_t)(bn * 256 + (tid >> 3)) * 2048 + gs * 8;
  const int dstA = tid * 16;
  const int dstB = 16384 + tid * 16;

  const int lane = tid & 63, wid = tid >> 6;
  const int wr = wid >> 2, wcn = wid & 3;
  const int lr = lane & 15, hi = lane >> 4;
  int aoff[4][2], boff[4][2];
#pragma unroll
  for (int m = 0; m < 4; ++m) {
    int row = wr * 64 + m * 16 + lr;
#pragma unroll
    for (int k = 0; k < 2; ++k)
      aoff[m][k] = row * 128 + ((((k * 4 + hi)) ^ (row & 7)) << 4);
  }
#pragma unroll
  for (int n = 0; n < 4; ++n) {
    int row = wcn * 64 + n * 16 + lr;
#pragma unroll
    for (int k = 0; k < 2; ++k)
      boff[n][k] = 16384 + row * 128 + ((((k * 4 + hi)) ^ (row & 7)) << 4);
  }

  f32x4 acc[4][4];
#pragma unroll
  for (int m = 0; m < 4; ++m)
#pragma unroll
    for (int n = 0; n < 4; ++n) {
      f32x4 z = {0.f, 0.f, 0.f, 0.f};
      acc[m][n] = z;
    }

#define STG_A(c, t_) do {                                                   \
    const unsigned short* _s = Abase + (t_) * 64;                           \
    async_cp16(smem + (c) * 49152 + dstA, _s);                              \
    async_cp16(smem + (c) * 49152 + dstA + 8192, _s + 64 * 2048);           \
  } while (0)
#define STG_B(c, t_) do {                                                   \
    const unsigned short* _s = Bbase + (t_) * 64;                           \
    async_cp16(smem + (c) * 49152 + dstB, _s);                              \
    async_cp16(smem + (c) * 49152 + dstB + 8192, _s + 64 * 2048);           \
    async_cp16(smem + (c) * 49152 + dstB + 16384, _s + 128 * 2048);         \
    async_cp16(smem + (c) * 49152 + dstB + 24576, _s + 192 * 2048);         \
  } while (0)

  auto tile = [&](int T, int CC, bool DO_A, bool DO_B, int VM) __attribute__((always_inline)) {
    const char* Sb = smem + CC * 49152;
    bf16x8 a0[4], b0[4], a1[4], b1[4];
#pragma unroll
    for (int m = 0; m < 4; ++m) a0[m] = *(const bf16x8*)(Sb + aoff[m][0]);
#pragma unroll
    for (int n = 0; n < 4; ++n) b0[n] = *(const bf16x8*)(Sb + boff[n][0]);
    if (DO_A) STG_A(CC ^ 1, T + 1);
    asm volatile("s_waitcnt lgkmcnt(0)" ::: "memory");
    __builtin_amdgcn_sched_barrier(0);
    __builtin_amdgcn_s_setprio(1);
#pragma unroll
    for (int m = 0; m < 4; ++m) {
      acc[m][0] = __builtin_amdgcn_mfma_f32_16x16x32_bf16(a0[m], b0[0], acc[m][0], 0, 0, 0);
      acc[m][1] = __builtin_amdgcn_mfma_f32_16x16x32_bf16(a0[m], b0[1], acc[m][1], 0, 0, 0);
    }
    __builtin_amdgcn_s_setprio(0);
    __builtin_amdgcn_sched_barrier(0);
    // k1 reads issue here, hidden under the second MFMA half
#pragma unroll
    for (int m = 0; m < 4; ++m) a1[m] = *(const bf16x8*)(Sb + aoff[m][1]);
#pragma unroll
    for (int n = 0; n < 4; ++n) b1[n] = *(const bf16x8*)(Sb + boff[n][1]);
    __builtin_amdgcn_sched_barrier(0);
    __builtin_amdgcn_s_setprio(1);
#pragma unroll
    for (int m = 0; m < 4; ++m) {
      acc[m][2] = __builtin_amdgcn_mfma_f32_16x16x32_bf16(a0[m], b0[2], acc[m][2], 0, 0, 0);
      acc[m][3] = __builtin_amdgcn_mfma_f32_16x16x32_bf16(a0[m], b0[3], acc[m][3], 0, 0, 0);
    }
    __builtin_amdgcn_s_setprio(0);
    __builtin_amdgcn_s_barrier();
    __builtin_amdgcn_sched_barrier(0);
    asm volatile("s_waitcnt lgkmcnt(0)" ::: "memory");
    __builtin_amdgcn_sched_barrier(0);
    if (DO_B) STG_B(CC, T + 2);
    __builtin_amdgcn_s_setprio(1);
#pragma unroll
    for (int m = 0; m < 4; ++m)
#pragma unroll
      for (int n = 0; n < 4; ++n)
        acc[m][n] = __builtin_amdgcn_mfma_f32_16x16x32_bf16(a1[m], b1[n], acc[m][n], 0, 0, 0);
    __builtin_amdgcn_s_setprio(0);
    if (VM == 0) asm volatile("s_waitcnt vmcnt(4)" ::: "memory");
    else if (VM == 1) asm volatile("s_waitcnt vmcnt(0)" ::: "memory");
    if (VM != 2) {
      __builtin_amdgcn_s_barrier();
      __builtin_amdgcn_sched_barrier(0);
    }
  };

  STG_B(0, 0);
  STG_A(0, 0);
  STG_B(1, 1);
  asm volatile("s_waitcnt vmcnt(4)" ::: "memory");
  __builtin_amdgcn_s_barrier();
  __builtin_amdgcn_sched_barrier(0);

  for (int it = 0; it < 15; ++it) {
    tile(2 * it, 0, true, true, 0);
    tile(2 * it + 1, 1, true, true, 0);
  }
  tile(30, 0, true, false, 1);
  tile(31, 1, false, false, 2);

  // ---- epilogue ----
  const int row_b = bm * 128 + wr * 64 + hi * 4;
  const int col_b = bn * 256 + wcn * 64 + lr;
  if (EPI == 0) {
#pragma unroll
    for (int m = 0; m < 4; ++m)
#pragma unroll
      for (int n = 0; n < 4; ++n) {
        int col = col_b + n * 16;
#pragma unroll
        for (int j = 0; j < 4; ++j) {
          int row = row_b + m * 16 + j;
          C0[(size_t)row * 2048 + col] = acc[m][n][j];
        }
      }
  } else {
    const int sel = bn >> 3;  // 0:q 1:k 2:v (2048-wide each)
#pragma unroll
    for (int m = 0; m < 4; ++m) {
#pragma unroll
      for (int n = 0; n < 4; ++n) {
        int col = col_b + n * 16;
        int hh = (col >> 7) & 15, d = col & 127;
        if (sel == 2) {
#pragma unroll
          for (int j = 0; j < 4; ++j) {
            int row = row_b + m * 16 + j;
            int b = row >> 11, s = row & 2047;
            Cv[((size_t)(b * NH + hh) * S_LEN + s) * DHD + d] = f2bf(acc[m][n][j]);
          }
        } else {
          unsigned short* dst = sel ? Ck : Cq;
          int dj = d >> 1;
          float sgn = (d & 1) ? 1.f : -1.f;
#pragma unroll
          for (int j = 0; j < 4; ++j) {
            int row = row_b + m * 16 + j;
            int b = row >> 11, s = row & 2047;
            float v = acc[m][n][j];
            float pp = __shfl_xor(v, 1);
            float cc = cosT[(s << 6) + dj];
            float sn = sinT[(s << 6) + dj];
            dst[((size_t)(b * NH + hh) * S_LEN + s) * DHD + d] = f2bf(v * cc + sgn * pp * sn);
          }
        }
      }
    }
  }
#undef STG_A
#undef STG_B
}

// ---------------- causal flash attention (R5 body + XCD-local head mapping) ----
// Q,K,V: [B][H][S][DH] bf16.  O: [B][S][H][DH] bf16.
// 1-D grid 512: lid = (hb&7) + 8*pq + 128*(hb>>3) -> XCD = lid%8 = hb&7,
// so each XCD owns 4 complete head-batches (K/V 4 MB = L2-resident).
__global__ __launch_bounds__(256) void k_flash_attn(const unsigned short* __restrict__ Qg,
                                                    const unsigned short* __restrict__ Kg,
                                                    const unsigned short* __restrict__ Vg,
                                                    unsigned short* __restrict__ Og) {
  __shared__ unsigned short K_lds[2][64 * 128];   // [kv][dh], XOR-swizzled slots
  __shared__ unsigned short VT_lds[2][128 * 64];  // [dh][pos(kv)], XOR-swizzled

  const int lid = blockIdx.x;
  const int pq = (lid >> 3) & 15;
  const int hb = ((lid >> 7) << 3) | (lid & 7);   // head-batch 0..31
  const int h = hb & 15, b = hb >> 4;

  const int t = threadIdx.x;
  const int lane = t & 63, wave = t >> 6;
  const int hi = lane >> 4, lr = lane & 15;

  const size_t head = (size_t)(b * NH + h) * (size_t)(S_LEN * DHD);
  const unsigned short* Q = Qg + head;
  const unsigned short* Kp = Kg + head;
  const unsigned short* Vp = Vg + head;

  const int kr0 = t >> 4;
  const int kgc = (t & 15) ^ (kr0 & 7);
  const unsigned short* Kbase = Kp + (size_t)kr0 * DHD + kgc * 8;
  const int kdst = t * 16;

  const int vdc = t & 15, vsp0 = t >> 4;
  const unsigned short* Vbase = Vp + (size_t)(2 * vsp0) * DHD + vdc * 8;
  const int bo0 = 16 * ((vsp0 >> 1) & 3) + 8 * ((vsp0 >> 3) & 1) + 4 * (vsp0 & 1);

  const float sc = 0.08838834764831845f;  // 1/sqrt(128)

  for (int pass = 0; pass < 2; ++pass) {
    const int qt = (pass == 0) ? pq : (31 - pq);
    const int nt = qt + 1;
    const int qbase = qt * 64 + wave * 16;
    const int qrow = qbase + lr;

    bf16x8 qf[4];
    {
      const unsigned short* qr_ = Q + (size_t)(qbase + lr) * DHD;
#pragma unroll
      for (int kc = 0; kc < 4; ++kc) qf[kc] = *(const bf16x8*)(qr_ + kc * 32 + hi * 8);
    }

    f32x4 of[8];
#pragma unroll
    for (int i = 0; i < 8; ++i) {
      f32x4 z = {0.f, 0.f, 0.f, 0.f};
      of[i] = z;
    }
    float mS = -INFINITY;
    float lsum = 0.f;

    // prologue: stage tile 0 into buffer 0
    {
#pragma unroll
      for (int i = 0; i < 4; ++i)
        async_cp16((char*)K_lds[0] + kdst + i * 4096, Kbase + (size_t)(16 * i) * DHD);
      ushort8 va0 = *(const ushort8*)(Vbase);
      ushort8 vb0 = *(const ushort8*)(Vbase + DHD);
      ushort8 va1 = *(const ushort8*)(Vbase + (size_t)32 * DHD);
      ushort8 vb1 = *(const ushort8*)(Vbase + (size_t)33 * DHD);
#pragma unroll
      for (int j = 0; j < 8; ++j) {
        int row = vdc * 8 + j;
        int swz = ((j ^ vdc) & 7) << 4;
        *(unsigned int*)((char*)VT_lds[0] + row * 128 + (bo0 ^ swz)) =
            (unsigned int)va0[j] | ((unsigned int)vb0[j] << 16);
        *(unsigned int*)((char*)VT_lds[0] + row * 128 + ((bo0 | 64) ^ swz)) =
            (unsigned int)va1[j] | ((unsigned int)vb1[j] << 16);
      }
    }
    __syncthreads();

    for (int tt = 0; tt < nt; ++tt) {
      const int cur = tt & 1;
      const int kv0 = tt * 64;
      const bool more = (tt + 1 < nt);
      const bool diag = (tt == qt);

      // issue next tile's loads (K async->LDS, V->regs)
      ushort8 va0, vb0, va1, vb1;
      if (more) {
        const unsigned short* ks = Kbase + (size_t)(kv0 + 64) * DHD;
#pragma unroll
        for (int i = 0; i < 4; ++i)
          async_cp16((char*)K_lds[cur ^ 1] + kdst + i * 4096, ks + (size_t)(16 * i) * DHD);
        const unsigned short* vs = Vbase + (size_t)(kv0 + 64) * DHD;
        va0 = *(const ushort8*)(vs);
        vb0 = *(const ushort8*)(vs + DHD);
        va1 = *(const ushort8*)(vs + (size_t)32 * DHD);
        vb1 = *(const ushort8*)(vs + (size_t)33 * DHD);
      }

      // QK^T swapped: lane q=lr, kv=kv0+16n+4*hi+reg
      const char* Kb = (const char*)K_lds[cur];
      f32x4 sf[4];
#pragma unroll
      for (int n = 0; n < 4; ++n) {
        f32x4 z = {0.f, 0.f, 0.f, 0.f};
        sf[n] = z;
      }
      __builtin_amdgcn_s_setprio(1);
#pragma unroll
      for (int n = 0; n < 4; ++n) {
        const int kr = n * 16 + lr;
        const int kswz = (kr & 7) << 4;
#pragma unroll
        for (int kc = 0; kc < 4; ++kc) {
          bf16x8 kf = *(const bf16x8*)(Kb + kr * 256 + ((kc * 64 + hi * 16) ^ kswz));
          sf[n] = __builtin_amdgcn_mfma_f32_16x16x32_bf16(kf, qf[kc], sf[n], 0, 0, 0);
        }
      }
      __builtin_amdgcn_s_setprio(0);

      // in-register masked online softmax (per-lane q-row)
      float p[4][4];
      float mx = -INFINITY;
      if (diag) {
#pragma unroll
        for (int n = 0; n < 4; ++n)
#pragma unroll
          for (int j = 0; j < 4; ++j) {
            int kvcol = kv0 + n * 16 + hi * 4 + j;
            float v = (kvcol > qrow) ? -INFINITY : sf[n][j];
            p[n][j] = v;
            mx = fmaxf(mx, v);
          }
      } else {
#pragma unroll
        for (int n = 0; n < 4; ++n)
#pragma unroll
          for (int j = 0; j < 4; ++j) {
            float v = sf[n][j];
            p[n][j] = v;
            mx = fmaxf(mx, v);
          }
      }
      mx = fmaxf(mx, __shfl_xor(mx, 16));
      mx = fmaxf(mx, __shfl_xor(mx, 32));
      float mn = fmaxf(mS, mx);
      float corr = __expf((mS - mn) * sc);
      mS = mn;
      float mns = mn * sc;
      float rs = 0.f;
#pragma unroll
      for (int n = 0; n < 4; ++n)
#pragma unroll
        for (int j = 0; j < 4; ++j) {
          float e = __expf(__builtin_fmaf(p[n][j], sc, -mns));
          p[n][j] = e;
          rs += e;
        }
      rs += __shfl_xor(rs, 16);
      rs += __shfl_xor(rs, 32);
      lsum = lsum * corr + rs;

      // pack P to bf16 (lane-local; feeds PV A-operand directly)
      unsigned int pk[4][2];
#pragma unroll
      for (int n = 0; n < 4; ++n) {
        pk[n][0] = cvt_pk_bf16(p[n][0], p[n][1]);
        pk[n][1] = cvt_pk_bf16(p[n][2], p[n][3]);
      }

      // rescale O: corr for q-row (qbase+hi*4+j) lives in lane (hi*4+j)
      float corrb[4];
#pragma unroll
      for (int j = 0; j < 4; ++j) corrb[j] = __shfl(corr, hi * 4 + j);
#pragma unroll
      for (int nd = 0; nd < 8; ++nd)
#pragma unroll
        for (int j = 0; j < 4; ++j) of[nd][j] *= corrb[j];

      // PV: O[16 q][128 dh] += P * V (V stored kv-permuted, A is lane-local)
      const char* Vb = (const char*)VT_lds[cur];
      __builtin_amdgcn_s_setprio(1);
#pragma unroll
      for (int kc = 0; kc < 2; ++kc) {
        union { unsigned int u[4]; bf16x8 v; } pa;
        pa.u[0] = pk[2 * kc][0];
        pa.u[1] = pk[2 * kc][1];
        pa.u[2] = pk[2 * kc + 1][0];
        pa.u[3] = pk[2 * kc + 1][1];
#pragma unroll
        for (int nd = 0; nd < 8; ++nd) {
          const int vr = nd * 16 + lr;
          const int vswz = ((vr & 7) ^ ((vr >> 3) & 7)) << 4;
          bf16x8 vf = *(const bf16x8*)(Vb + vr * 128 + ((kc * 64 + hi * 16) ^ vswz));
          of[nd] = __builtin_amdgcn_mfma_f32_16x16x32_bf16(pa.v, vf, of[nd], 0, 0, 0);
        }
      }
      __builtin_amdgcn_s_setprio(0);

      // complete next tile's V staging (reg -> LDS, permuted+swizzled)
      if (more) {
        char* Vw = (char*)VT_lds[cur ^ 1];
#pragma unroll
        for (int j = 0; j < 8; ++j) {
          int row = vdc * 8 + j;
          int swz = ((j ^ vdc) & 7) << 4;
          *(unsigned int*)(Vw + row * 128 + (bo0 ^ swz)) =
              (unsigned int)va0[j] | ((unsigned int)vb0[j] << 16);
          *(unsigned int*)(Vw + row * 128 + ((bo0 | 64) ^ swz)) =
              (unsigned int)va1[j] | ((unsigned int)vb1[j] << 16);
        }
      }
      __syncthreads();
    }

    // epilogue: normalize, write [B][S][H][DH]
    float inv[4];
#pragma unroll
    for (int j = 0; j < 4; ++j) {
      float ls = __shfl(lsum, hi * 4 + j);
      inv[j] = 1.0f / ls;
    }
#pragma unroll
    for (int nd = 0; nd < 8; ++nd)
#pragma unroll
      for (int j = 0; j < 4; ++j) {
        int qr = qbase + hi * 4 + j;
        Og[((size_t)(b * S_LEN + qr) * NH + h) * DHD + nd * 16 + lr] = f2bf(of[nd][j] * inv[j]);
      }
  }
}

// ---------------- launch ----------------
extern "C" void kernel_launch(void* const* d_in, const int* in_sizes, int n_in,
                              void* d_out, int out_size, void* d_ws, size_t ws_size,
                              hipStream_t stream) {
  const float* x  = (const float*)d_in[0];
  const float* wq = (const float*)d_in[1];
  const float* wk = (const float*)d_in[2];
  const float* wv = (const float*)d_in[3];
  const float* wo = (const float*)d_in[4];
  float* out = (float*)d_out;

  char* ws = (char*)d_ws;
  unsigned short* xb    = (unsigned short*)(ws);              // 16 MB (reused as attn out)
  unsigned short* wqT   = (unsigned short*)(ws + 16777216);   // 8 MB each, contiguous -> [6144][2048]
  unsigned short* woT   = (unsigned short*)(ws + 41943040);
  unsigned short* qb    = (unsigned short*)(ws + 50331648);   // 16 MB each
  unsigned short* kb    = (unsigned short*)(ws + 67108864);
  unsigned short* vb    = (unsigned short*)(ws + 83886080);
  float*          cosT  = (float*)(ws + 100663296);           // 512 KB
  float*          sinT  = (float*)(ws + 101187584);
  unsigned short* attnb = xb;

  k_prep<<<8704, 256, 0, stream>>>(x, xb, cosT, sinT);
  dim3 tg(32, 32, 4);
  k_transpose_all<<<tg, 256, 0, stream>>>(wq, wk, wv, wo, wqT);

  // fused q/k/v projection: 32x24 tiles of 128x256 -> 768 blocks (3 even rounds)
  k_gemm128<1><<<768, 512, 0, stream>>>(xb, wqT, nullptr, qb, kb, vb, cosT, sinT, 6);

  // attention: 512 blocks, XCD-local head mapping (lid%8 = hb&7)
  k_flash_attn<<<512, 256, 0, stream>>>(qb, kb, vb, attnb);

  // output projection: 32x8 tiles -> 256 blocks (1 round)
  k_gemm128<0><<<256, 512, 0, stream>>>(attnb, woT, out, nullptr, nullptr, nullptr,
                                        nullptr, nullptr, 2);
}